// Round 4
// baseline (430.937 us; speedup 1.0000x reference)
//
#include <hip/hip_runtime.h>
#include <hip/hip_bf16.h>
#include <stdint.h>

typedef __attribute__((ext_vector_type(8))) short short8;
typedef __attribute__((ext_vector_type(4))) float f32x4;

#define N_NODES 16384
#define D_IN    512
#define D_HID   256
#define D_OUT   64
#define S_SAMP  4096

__device__ __forceinline__ unsigned short f2bf(float f) {
  __hip_bfloat16 h = __float2bfloat16(f);
  union { __hip_bfloat16 h; unsigned short u; } cv; cv.h = h; return cv.u;
}

// C += scale * bf16(optional-relu(A_f32[gathered rows])) @ Bt^T
// A: [M][lda] f32 (row gather via arow). Bt: [BN][K] bf16 row-major (N==BN).
// C: [M][ldc] f32, pre-zeroed, atomic accumulate. Grid = (M/BM) * kChunks.
// 2-phase pipeline: double-buffered As/Bs (BK=32 keeps LDS == single-buffer BK=64),
// stage(t+1) issued before compute(t), ONE barrier per K-step.
template<int BM, int BN, int BK, bool RELU_A, int MINW>
__global__ __launch_bounds__(256, MINW)
void gemm_tn(const float* __restrict__ A, int lda,
             const int* __restrict__ arow,
             const unsigned short* __restrict__ Bt, int ldb,
             float* __restrict__ C, int ldc,
             int K, int kChunks, float scale)
{
  static_assert(BM == 64 && (BK == 32 || BK == 64) && (BN == 64 || BN == 256), "tile");
  constexpr int CH    = BK / 8;      // 16B chunks per LDS row
  constexpr int RPS   = 512 / BK;    // rows per 1KB slab (64 lanes x 16B)
  constexpr int SLABS = BN / RPS;
  constexpr int SLABW = SLABS / 4;   // slabs per wave
  constexpr int AV    = BK / 16;     // f32x4 loads per thread (A tile)
  constexpr int AC    = BK / 32;     // short8 chunks per thread (A tile)

  const int mt  = blockIdx.x / kChunks;
  const int kc  = blockIdx.x % kChunks;
  const int kLen = K / kChunks;
  const int k0   = kc * kLen;
  const int nt   = kLen / BK;
  const int tid  = threadIdx.x;
  const int lane = tid & 63;
  const int wid  = tid >> 6;
  const int l16  = lane & 15;
  const int lg   = lane >> 4;

  __shared__ unsigned short As[2][BM * BK];
  __shared__ unsigned short Bs[2][BN * BK];

  constexpr int WN  = (BN == 256) ? 4 : 2;
  constexpr int WM  = 4 / WN;
  constexpr int WTM = BM / WM;
  constexpr int WTN = BN / WN;
  constexpr int MF  = WTM / 16;
  constexpr int NF  = WTN / 16;
  const int wrow = wid / WN;
  const int wcol = wid % WN;

  f32x4 acc[MF][NF] = {};

  // ---- A staging mapping: 256 threads, 4 per row, BK/4 f32 each ----
  const int am   = tid >> 2;
  const int aseg = tid & 3;
  const int arowIdx = mt * BM + am;
  const size_t rowg = arow ? (size_t)arow[arowIdx] : (size_t)arowIdx;
  const float* aBase = A + rowg * (size_t)lda + k0 + aseg * (BK / 4);

  // ---- B staging: global_load_lds, linear LDS dest + pre-swizzled source ----
  const int brow = lane / CH;                          // row within slab
  const int bcol = 8 * ((lane % CH) ^ (brow & (CH - 1)));
  const unsigned short* bSrc = Bt + (size_t)brow * ldb + k0 + bcol;

  f32x4 av[AV];

  auto loadA = [&](int ks) {
    #pragma unroll
    for (int i = 0; i < AV; ++i) av[i] = *(const f32x4*)(aBase + ks + 4 * i);
  };
  auto writeA = [&](int buf) {
    if (RELU_A) {
      #pragma unroll
      for (int i = 0; i < AV; ++i)
        #pragma unroll
        for (int j = 0; j < 4; ++j) av[i][j] = fmaxf(av[i][j], 0.f);
    }
    #pragma unroll
    for (int c = 0; c < AC; ++c) {
      short8 s;
      s[0]=f2bf(av[2*c][0]);   s[1]=f2bf(av[2*c][1]);
      s[2]=f2bf(av[2*c][2]);   s[3]=f2bf(av[2*c][3]);
      s[4]=f2bf(av[2*c+1][0]); s[5]=f2bf(av[2*c+1][1]);
      s[6]=f2bf(av[2*c+1][2]); s[7]=f2bf(av[2*c+1][3]);
      const int g = (aseg * AC + c) ^ (am & (CH - 1));
      *(short8*)&As[buf][am * BK + g * 8] = s;
    }
  };
  auto issueB = [&](int buf, int ks) {
    #pragma unroll
    for (int i = 0; i < SLABW; ++i) {
      const int s = wid * SLABW + i;
      __builtin_amdgcn_global_load_lds(
          (const __attribute__((address_space(1))) uint32_t*)(bSrc + (size_t)s * RPS * ldb + ks),
          (__attribute__((address_space(3))) uint32_t*)(&Bs[buf][s * 512]),
          16, 0, 0);
    }
  };
  auto compute = [&](int buf) {
    #pragma unroll
    for (int kk = 0; kk < BK / 32; ++kk) {
      const int gk = kk * 4 + lg;
      short8 af[MF], bfr[NF];
      #pragma unroll
      for (int fm = 0; fm < MF; ++fm) {
        const int m = wrow * WTM + fm * 16 + l16;
        af[fm] = *(const short8*)&As[buf][m * BK + ((gk ^ (m & (CH - 1))) * 8)];
      }
      #pragma unroll
      for (int fn = 0; fn < NF; ++fn) {
        const int n = wcol * WTN + fn * 16 + l16;
        bfr[fn] = *(const short8*)&Bs[buf][n * BK + ((gk ^ (n & (CH - 1))) * 8)];
      }
      #pragma unroll
      for (int fm = 0; fm < MF; ++fm)
        #pragma unroll
        for (int fn = 0; fn < NF; ++fn)
          acc[fm][fn] = __builtin_amdgcn_mfma_f32_16x16x32_bf16(
              af[fm], bfr[fn], acc[fm][fn], 0, 0, 0);
    }
  };

  // ---- prologue: stage tile 0 ----
  loadA(0);
  issueB(0, 0);
  writeA(0);
  __syncthreads();      // drains vmcnt (B-lds) + lgkm (A ds_write)

  int cur = 0;
  for (int t = 0; t < nt; ++t) {
    const bool more = (t + 1 < nt);
    if (more) {
      loadA((t + 1) * BK);          // issue A reg-loads early (latency under compute)
      issueB(cur ^ 1, (t + 1) * BK);
    }
    compute(cur);
    if (more) writeA(cur ^ 1);      // cvt + ds_write after compute
    __syncthreads();
    cur ^= 1;
  }

  // ---- epilogue: scaled f32 atomic add ----
  #pragma unroll
  for (int fm = 0; fm < MF; ++fm)
    #pragma unroll
    for (int fn = 0; fn < NF; ++fn)
      #pragma unroll
      for (int j = 0; j < 4; ++j) {
        const int r = mt * BM + wrow * WTM + fm * 16 + lg * 4 + j;
        const int c = wcol * WTN + fn * 16 + l16;
        atomicAdd(&C[(size_t)r * ldc + c], scale * acc[fm][fn][j]);
      }
}

// transpose-convert weights: W1t[j][i] = bf16(W1[i][j]), W2t likewise
__global__ void conv_w_t(const float* __restrict__ W1, const float* __restrict__ W2,
                         unsigned short* __restrict__ W1t, unsigned short* __restrict__ W2t) {
  const int idx = blockIdx.x * 256 + threadIdx.x;
  if (idx < D_IN * D_HID) {
    const int j = idx / D_IN, i = idx % D_IN;
    W1t[idx] = f2bf(W1[(size_t)i * D_HID + j]);
  }
  if (idx < D_HID * D_OUT) {
    const int j = idx / D_HID, i = idx % D_HID;
    W2t[idx] = f2bf(W2[(size_t)i * D_OUT + j]);
  }
}

// BextT[c][rows[r]] = bf16(relu(G[r][c] + bias[c]))   (BextT pre-zeroed, [ncol][N_NODES])
__global__ void ep_scatter_t(const float* __restrict__ G, const float* __restrict__ bias,
                             const int* __restrict__ rows, unsigned short* __restrict__ BextT,
                             int ncol, int total) {
  const int idx = blockIdx.x * 256 + threadIdx.x;
  if (idx >= total) return;
  const int c = idx / S_SAMP;
  const int r = idx & (S_SAMP - 1);
  float v = G[(size_t)r * ncol + c] + bias[c];
  v = v > 0.f ? v : 0.f;
  BextT[(size_t)c * N_NODES + rows[r]] = f2bf(v);
}

extern "C" void kernel_launch(void* const* d_in, const int* in_sizes, int n_in,
                              void* d_out, int out_size, void* d_ws, size_t ws_size,
                              hipStream_t stream) {
  const float* X     = (const float*)d_in[0];
  const float* A_hat = (const float*)d_in[1];
  const float* W1    = (const float*)d_in[2];
  const float* b1    = (const float*)d_in[3];
  const float* W2    = (const float*)d_in[4];
  const float* b2    = (const float*)d_in[5];
  const int*   l0    = (const int*)d_in[6];
  const int*   l1    = (const int*)d_in[7];
  float* out = (float*)d_out;

  if (ws_size < (size_t)(20u << 20)) return;
  char* ws = (char*)d_ws;
  // zeroed region: [HextT 8M][PextT 2M][G1 4M][G2 4M][G3 1M] = 19 MB contiguous
  unsigned short* HextT = (unsigned short*)(ws);                      // [256][16384]
  unsigned short* PextT = (unsigned short*)(ws + (8  << 20));         // [64][16384]
  float* G1 = (float*)(ws + (10 << 20));                              // [S][256]
  float* G2 = (float*)(ws + (14 << 20));                              // [S][256]
  float* G3 = (float*)(ws + (18 << 20));                              // [S][64]
  unsigned short* W1t = (unsigned short*)(ws + (19 << 20));           // [256][512]
  unsigned short* W2t = (unsigned short*)(ws + (19 << 20) + (256 << 10)); // [64][256]

  hipMemsetAsync(ws,  0, (size_t)(19u << 20), stream);
  hipMemsetAsync(out, 0, (size_t)N_NODES * D_OUT * 4, stream);

  conv_w_t<<<512, 256, 0, stream>>>(W1, W2, W1t, W2t);

  // L0 feature: G1 = X[l0] @ W1          M=4096 K=512 N=256 (512 blocks, 2/CU)
  gemm_tn<64, 256, 32, false, 4><<<(S_SAMP / 64) * 8, 256, 0, stream>>>(
      X, D_IN, l0, W1t, D_IN, G1, D_HID, D_IN, 8, 1.0f);
  // HextT[:, l0[j]] = bf16(relu(G1[j] + b1))
  ep_scatter_t<<<(S_SAMP * D_HID + 255) / 256, 256, 0, stream>>>(
      G1, b1, l0, HextT, D_HID, S_SAMP * D_HID);

  // L0 agg: G2 = 4 * A_hat[l1, :] @ Hext  M=4096 K=16384 N=256 (1024 blocks, 4/CU, 40KB LDS)
  gemm_tn<64, 256, 32, false, 4><<<(S_SAMP / 64) * 16, 256, 0, stream>>>(
      A_hat, N_NODES, l1, HextT, N_NODES, G2, D_HID, N_NODES, 16, 4.0f);

  // L1 feature: G3 = relu(G2) @ W2        M=4096 K=256 N=64  (relu fused into A-path)
  gemm_tn<64, 64, 32, true, 8><<<(S_SAMP / 64) * 4, 256, 0, stream>>>(
      G2, D_HID, nullptr, W2t, D_HID, G3, D_OUT, D_HID, 4, 1.0f);
  // PextT[:, l1[j]] = bf16(relu(G3[j] + b2))
  ep_scatter_t<<<(S_SAMP * D_OUT + 255) / 256, 256, 0, stream>>>(
      G3, b2, l1, PextT, D_OUT, S_SAMP * D_OUT);

  // L1 agg: out = 4 * A_hat @ Pext        M=16384 K=16384 N=64 (2048 blocks, 8/CU, 16KB LDS)
  gemm_tn<64, 64, 32, false, 8><<<(N_NODES / 64) * 8, 256, 0, stream>>>(
      A_hat, N_NODES, nullptr, PextT, N_NODES, out, D_OUT, N_NODES, 8, 4.0f);
}

// Round 5
// 423.627 us; speedup vs baseline: 1.0173x; 1.0173x over previous
//
#include <hip/hip_runtime.h>
#include <hip/hip_bf16.h>
#include <stdint.h>

typedef __attribute__((ext_vector_type(8))) short short8;
typedef __attribute__((ext_vector_type(4))) float f32x4;

#define N_NODES 16384
#define D_IN    512
#define D_HID   256
#define D_OUT   64
#define S_SAMP  4096

__device__ __forceinline__ unsigned short f2bf(float f) {
  __hip_bfloat16 h = __float2bfloat16(f);
  union { __hip_bfloat16 h; unsigned short u; } cv; cv.h = h; return cv.u;
}

// ---------------------------------------------------------------------------
// gemm_direct: C += scale * bf16(A_f32[gathered rows]) @ Bt^T
// BM=64, 4 waves, WN=1: wave w owns rows [w*16, w*16+16) x all BN cols.
// A loaded DIRECTLY from global in MFMA fragment layout (no LDS, no barrier
// dependency), register-double-buffered. B staged via global_load_lds into
// double-buffered LDS; ONE barrier per K-step; B loads in flight across the
// entire compute phase. Requires nt = K/kChunks/BK even.
// ---------------------------------------------------------------------------
template<int BN, int BK, int MINW>
__global__ __launch_bounds__(256, MINW)
void gemm_direct(const float* __restrict__ A, int lda,
                 const int* __restrict__ arow,
                 const unsigned short* __restrict__ Bt, int ldb,
                 float* __restrict__ C, int ldc,
                 int K, int kChunks, float scale)
{
  constexpr int NF    = BN / 16;
  constexpr int KKS   = BK / 32;     // 16x16x32 MFMA steps per K-step
  constexpr int CH    = BK / 8;      // 16B chunks per LDS row
  constexpr int RPS   = 512 / BK;    // B rows per 1KB slab
  constexpr int SLABS = BN / RPS;
  constexpr int SLABW = SLABS / 4;   // slabs per wave

  const int mt   = blockIdx.x / kChunks;
  const int kc   = blockIdx.x % kChunks;
  const int kLen = K / kChunks;
  const int k0   = kc * kLen;
  const int nt   = kLen / BK;        // must be even
  const int tid  = threadIdx.x;
  const int lane = tid & 63;
  const int wid  = tid >> 6;
  const int l16  = lane & 15;
  const int lg   = lane >> 4;

  __shared__ unsigned short Bs[2][BN * BK];

  // A: fragment-layout direct load. lane (l16,lg) -> row l16, k = lg*8..+7.
  const int r = mt * 64 + wid * 16 + l16;
  const size_t ra = arow ? (size_t)arow[r] : (size_t)r;
  const float* aPtr = A + ra * (size_t)lda + k0 + lg * 8;

  // B staging: linear LDS dest + pre-swizzled global source.
  const int brow = lane / CH;
  const int bcol = 8 * ((lane % CH) ^ (brow & (CH - 1)));
  const unsigned short* bSrc = Bt + (size_t)brow * ldb + k0 + bcol;

  f32x4 acc[NF] = {};
  f32x4 avA[2 * KKS], avB[2 * KKS];

  auto issueB = [&](int buf, int t) {
    #pragma unroll
    for (int i = 0; i < SLABW; ++i) {
      const int s = wid * SLABW + i;
      __builtin_amdgcn_global_load_lds(
          (const __attribute__((address_space(1))) uint32_t*)(bSrc + (size_t)s * RPS * ldb + t * BK),
          (__attribute__((address_space(3))) uint32_t*)(&Bs[buf][s * 512]),
          16, 0, 0);
    }
  };
  auto loadA = [&](f32x4 (&av)[2 * KKS], int t) {
    #pragma unroll
    for (int kk = 0; kk < KKS; ++kk) {
      av[2 * kk]     = *(const f32x4*)(aPtr + t * BK + kk * 32);
      av[2 * kk + 1] = *(const f32x4*)(aPtr + t * BK + kk * 32 + 4);
    }
  };
  auto compute = [&](int buf, f32x4 (&av)[2 * KKS]) {
    #pragma unroll
    for (int kk = 0; kk < KKS; ++kk) {
      short8 af;
      af[0] = f2bf(av[2*kk][0]);   af[1] = f2bf(av[2*kk][1]);
      af[2] = f2bf(av[2*kk][2]);   af[3] = f2bf(av[2*kk][3]);
      af[4] = f2bf(av[2*kk+1][0]); af[5] = f2bf(av[2*kk+1][1]);
      af[6] = f2bf(av[2*kk+1][2]); af[7] = f2bf(av[2*kk+1][3]);
      #pragma unroll
      for (int fn = 0; fn < NF; ++fn) {
        const int n = fn * 16 + l16;
        short8 b = *(const short8*)&Bs[buf][n * BK + (((kk * 4 + lg) ^ (n & (CH - 1))) * 8)];
        acc[fn] = __builtin_amdgcn_mfma_f32_16x16x32_bf16(af, b, acc[fn], 0, 0, 0);
      }
    }
  };

  // prologue
  loadA(avA, 0);
  issueB(0, 0);

  for (int t = 0; t + 2 <= nt; t += 2) {
    __syncthreads();                      // B(t) landed (vmcnt drained); buf1 free
    if (t + 1 < nt) { issueB(1, t + 1); loadA(avB, t + 1); }
    compute(0, avA);
    __syncthreads();                      // B(t+1) landed; buf0 free
    if (t + 2 < nt) { issueB(0, t + 2); loadA(avA, t + 2); }
    compute(1, avB);
  }

  // epilogue: scaled f32 atomic add. C/D frag: col=l16, row=lg*4+j.
  #pragma unroll
  for (int fn = 0; fn < NF; ++fn)
    #pragma unroll
    for (int j = 0; j < 4; ++j) {
      const int rr = mt * 64 + wid * 16 + lg * 4 + j;
      const int cc = fn * 16 + l16;
      atomicAdd(&C[(size_t)rr * ldc + cc], scale * acc[fn][j]);
    }
}

// ---------------------------------------------------------------------------
// gemm_tn (R4 form): LDS-staged A with optional relu — used for the two small
// feature GEMMs (gemm1, gemm3) only.
// ---------------------------------------------------------------------------
template<int BM, int BN, int BK, bool RELU_A, int MINW>
__global__ __launch_bounds__(256, MINW)
void gemm_tn(const float* __restrict__ A, int lda,
             const int* __restrict__ arow,
             const unsigned short* __restrict__ Bt, int ldb,
             float* __restrict__ C, int ldc,
             int K, int kChunks, float scale)
{
  static_assert(BM == 64 && (BK == 32 || BK == 64) && (BN == 64 || BN == 256), "tile");
  constexpr int CH    = BK / 8;
  constexpr int RPS   = 512 / BK;
  constexpr int SLABS = BN / RPS;
  constexpr int SLABW = SLABS / 4;
  constexpr int AV    = BK / 16;
  constexpr int AC    = BK / 32;

  const int mt  = blockIdx.x / kChunks;
  const int kc  = blockIdx.x % kChunks;
  const int kLen = K / kChunks;
  const int k0   = kc * kLen;
  const int nt   = kLen / BK;
  const int tid  = threadIdx.x;
  const int lane = tid & 63;
  const int wid  = tid >> 6;
  const int l16  = lane & 15;
  const int lg   = lane >> 4;

  __shared__ unsigned short As[2][BM * BK];
  __shared__ unsigned short Bs[2][BN * BK];

  constexpr int WN  = (BN == 256) ? 4 : 2;
  constexpr int WM  = 4 / WN;
  constexpr int WTM = BM / WM;
  constexpr int WTN = BN / WN;
  constexpr int MF  = WTM / 16;
  constexpr int NF  = WTN / 16;
  const int wrow = wid / WN;
  const int wcol = wid % WN;

  f32x4 acc[MF][NF] = {};

  const int am   = tid >> 2;
  const int aseg = tid & 3;
  const int arowIdx = mt * BM + am;
  const size_t rowg = arow ? (size_t)arow[arowIdx] : (size_t)arowIdx;
  const float* aBase = A + rowg * (size_t)lda + k0 + aseg * (BK / 4);

  const int brow = lane / CH;
  const int bcol = 8 * ((lane % CH) ^ (brow & (CH - 1)));
  const unsigned short* bSrc = Bt + (size_t)brow * ldb + k0 + bcol;

  f32x4 av[AV];

  auto loadA = [&](int ks) {
    #pragma unroll
    for (int i = 0; i < AV; ++i) av[i] = *(const f32x4*)(aBase + ks + 4 * i);
  };
  auto writeA = [&](int buf) {
    if (RELU_A) {
      #pragma unroll
      for (int i = 0; i < AV; ++i)
        #pragma unroll
        for (int j = 0; j < 4; ++j) av[i][j] = fmaxf(av[i][j], 0.f);
    }
    #pragma unroll
    for (int c = 0; c < AC; ++c) {
      short8 s;
      s[0]=f2bf(av[2*c][0]);   s[1]=f2bf(av[2*c][1]);
      s[2]=f2bf(av[2*c][2]);   s[3]=f2bf(av[2*c][3]);
      s[4]=f2bf(av[2*c+1][0]); s[5]=f2bf(av[2*c+1][1]);
      s[6]=f2bf(av[2*c+1][2]); s[7]=f2bf(av[2*c+1][3]);
      const int g = (aseg * AC + c) ^ (am & (CH - 1));
      *(short8*)&As[buf][am * BK + g * 8] = s;
    }
  };
  auto issueB = [&](int buf, int ks) {
    #pragma unroll
    for (int i = 0; i < SLABW; ++i) {
      const int s = wid * SLABW + i;
      __builtin_amdgcn_global_load_lds(
          (const __attribute__((address_space(1))) uint32_t*)(bSrc + (size_t)s * RPS * ldb + ks),
          (__attribute__((address_space(3))) uint32_t*)(&Bs[buf][s * 512]),
          16, 0, 0);
    }
  };
  auto compute = [&](int buf) {
    #pragma unroll
    for (int kk = 0; kk < BK / 32; ++kk) {
      const int gk = kk * 4 + lg;
      short8 af[MF], bfr[NF];
      #pragma unroll
      for (int fm = 0; fm < MF; ++fm) {
        const int m = wrow * WTM + fm * 16 + l16;
        af[fm] = *(const short8*)&As[buf][m * BK + ((gk ^ (m & (CH - 1))) * 8)];
      }
      #pragma unroll
      for (int fn = 0; fn < NF; ++fn) {
        const int n = wcol * WTN + fn * 16 + l16;
        bfr[fn] = *(const short8*)&Bs[buf][n * BK + ((gk ^ (n & (CH - 1))) * 8)];
      }
      #pragma unroll
      for (int fm = 0; fm < MF; ++fm)
        #pragma unroll
        for (int fn = 0; fn < NF; ++fn)
          acc[fm][fn] = __builtin_amdgcn_mfma_f32_16x16x32_bf16(
              af[fm], bfr[fn], acc[fm][fn], 0, 0, 0);
    }
  };

  loadA(0);
  issueB(0, 0);
  writeA(0);
  __syncthreads();

  int cur = 0;
  for (int t = 0; t < nt; ++t) {
    const bool more = (t + 1 < nt);
    if (more) {
      loadA((t + 1) * BK);
      issueB(cur ^ 1, (t + 1) * BK);
    }
    compute(cur);
    if (more) writeA(cur ^ 1);
    __syncthreads();
    cur ^= 1;
  }

  #pragma unroll
  for (int fm = 0; fm < MF; ++fm)
    #pragma unroll
    for (int fn = 0; fn < NF; ++fn)
      #pragma unroll
      for (int j = 0; j < 4; ++j) {
        const int rr = mt * BM + wrow * WTM + fm * 16 + lg * 4 + j;
        const int cc = wcol * WTN + fn * 16 + l16;
        atomicAdd(&C[(size_t)rr * ldc + cc], scale * acc[fm][fn][j]);
      }
}

// transpose-convert weights: W1t[j][i] = bf16(W1[i][j]), W2t likewise
__global__ void conv_w_t(const float* __restrict__ W1, const float* __restrict__ W2,
                         unsigned short* __restrict__ W1t, unsigned short* __restrict__ W2t) {
  const int idx = blockIdx.x * 256 + threadIdx.x;
  if (idx < D_IN * D_HID) {
    const int j = idx / D_IN, i = idx % D_IN;
    W1t[idx] = f2bf(W1[(size_t)i * D_HID + j]);
  }
  if (idx < D_HID * D_OUT) {
    const int j = idx / D_HID, i = idx % D_HID;
    W2t[idx] = f2bf(W2[(size_t)i * D_OUT + j]);
  }
}

// BextT[c][rows[r]] = bf16(relu(G[r][c] + bias[c]))   (BextT pre-zeroed)
__global__ void ep_scatter_t(const float* __restrict__ G, const float* __restrict__ bias,
                             const int* __restrict__ rows, unsigned short* __restrict__ BextT,
                             int ncol, int total) {
  const int idx = blockIdx.x * 256 + threadIdx.x;
  if (idx >= total) return;
  const int c = idx / S_SAMP;
  const int r = idx & (S_SAMP - 1);
  float v = G[(size_t)r * ncol + c] + bias[c];
  v = v > 0.f ? v : 0.f;
  BextT[(size_t)c * N_NODES + rows[r]] = f2bf(v);
}

extern "C" void kernel_launch(void* const* d_in, const int* in_sizes, int n_in,
                              void* d_out, int out_size, void* d_ws, size_t ws_size,
                              hipStream_t stream) {
  const float* X     = (const float*)d_in[0];
  const float* A_hat = (const float*)d_in[1];
  const float* W1    = (const float*)d_in[2];
  const float* b1    = (const float*)d_in[3];
  const float* W2    = (const float*)d_in[4];
  const float* b2    = (const float*)d_in[5];
  const int*   l0    = (const int*)d_in[6];
  const int*   l1    = (const int*)d_in[7];
  float* out = (float*)d_out;

  if (ws_size < (size_t)(20u << 20)) return;
  char* ws = (char*)d_ws;
  unsigned short* HextT = (unsigned short*)(ws);                      // [256][16384] 8MB
  unsigned short* PextT = (unsigned short*)(ws + (8  << 20));         // [64][16384]  2MB
  float* G1 = (float*)(ws + (10 << 20));                              // [S][256] 4MB
  float* G2 = (float*)(ws + (14 << 20));                              // [S][256] 4MB
  float* G3 = (float*)(ws + (18 << 20));                              // [S][64]  1MB
  unsigned short* W1t = (unsigned short*)(ws + (19 << 20));           // [256][512]
  unsigned short* W2t = (unsigned short*)(ws + (19 << 20) + (256 << 10)); // [64][256]

  hipMemsetAsync(ws,  0, (size_t)(19u << 20), stream);
  hipMemsetAsync(out, 0, (size_t)N_NODES * D_OUT * 4, stream);

  conv_w_t<<<512, 256, 0, stream>>>(W1, W2, W1t, W2t);

  // L0 feature: G1 = X[l0] @ W1          M=4096 K=512 N=256
  gemm_tn<64, 256, 32, false, 4><<<(S_SAMP / 64) * 8, 256, 0, stream>>>(
      X, D_IN, l0, W1t, D_IN, G1, D_HID, D_IN, 8, 1.0f);
  ep_scatter_t<<<(S_SAMP * D_HID + 255) / 256, 256, 0, stream>>>(
      G1, b1, l0, HextT, D_HID, S_SAMP * D_HID);

  // L0 agg: G2 = 4 * A_hat[l1, :] @ Hext  M=4096 K=16384 N=256  (nt=32 even)
  gemm_direct<256, 32, 4><<<(S_SAMP / 64) * 16, 256, 0, stream>>>(
      A_hat, N_NODES, l1, HextT, N_NODES, G2, D_HID, N_NODES, 16, 4.0f);

  // L1 feature: G3 = relu(G2) @ W2        M=4096 K=256 N=64
  gemm_tn<64, 64, 32, true, 8><<<(S_SAMP / 64) * 4, 256, 0, stream>>>(
      G2, D_HID, nullptr, W2t, D_HID, G3, D_OUT, D_HID, 4, 1.0f);
  ep_scatter_t<<<(S_SAMP * D_OUT + 255) / 256, 256, 0, stream>>>(
      G3, b2, l1, PextT, D_OUT, S_SAMP * D_OUT);

  // L1 agg: out = 4 * A_hat @ Pext        M=16384 K=16384 N=64  (nt=32 even)
  gemm_direct<64, 64, 6><<<(N_NODES / 64) * 8, 256, 0, stream>>>(
      A_hat, N_NODES, nullptr, PextT, N_NODES, out, D_OUT, N_NODES, 8, 4.0f);
}

// Round 6
// 411.680 us; speedup vs baseline: 1.0468x; 1.0290x over previous
//
#include <hip/hip_runtime.h>
#include <hip/hip_bf16.h>
#include <stdint.h>

typedef __attribute__((ext_vector_type(8))) short short8;
typedef __attribute__((ext_vector_type(4))) float f32x4;

#define N_NODES 16384
#define D_IN    512
#define D_HID   256
#define D_OUT   64
#define S_SAMP  4096

__device__ __forceinline__ unsigned short f2bf(float f) {
  __hip_bfloat16 h = __float2bfloat16(f);
  union { __hip_bfloat16 h; unsigned short u; } cv; cv.h = h; return cv.u;
}

// ---------------------------------------------------------------------------
// gemm_tn — R2 baseline form: single-buffered As/Bs, BK=64, two barriers per
// K-step. Used for gemm1/gemm2/gemm3.
// ---------------------------------------------------------------------------
template<int BM, int BN, int BK, bool RELU_A>
__global__ __launch_bounds__(256)
void gemm_tn(const float* __restrict__ A, int lda,
             const int* __restrict__ arow,
             const unsigned short* __restrict__ Bt, int ldb,
             float* __restrict__ C, int ldc,
             int K, int kChunks, float scale)
{
  static_assert(BM == 64 && BK == 64 && (BN == 64 || BN == 256), "tile");
  constexpr int CH    = BK / 8;
  constexpr int RPS   = 512 / BK;
  constexpr int SLABS = BN / RPS;
  constexpr int SLABW = SLABS / 4;

  const int mt  = blockIdx.x / kChunks;
  const int kc  = blockIdx.x % kChunks;
  const int kLen = K / kChunks;
  const int k0   = kc * kLen;
  const int tid  = threadIdx.x;
  const int lane = tid & 63;
  const int wid  = tid >> 6;
  const int l16  = lane & 15;
  const int lg   = lane >> 4;

  __shared__ unsigned short As[BM * BK];
  __shared__ unsigned short Bs[BN * BK];

  constexpr int WN  = (BN == 256) ? 4 : 2;
  constexpr int WM  = 4 / WN;
  constexpr int WTM = BM / WM;
  constexpr int WTN = BN / WN;
  constexpr int MF  = WTM / 16;
  constexpr int NF  = WTN / 16;
  const int wrow = wid / WN;
  const int wcol = wid % WN;

  f32x4 acc[MF][NF] = {};

  const int am   = tid >> 2;
  const int aseg = tid & 3;
  const int arowIdx = mt * BM + am;
  const size_t rowg = arow ? (size_t)arow[arowIdx] : (size_t)arowIdx;
  const float* aBase = A + rowg * (size_t)lda + k0 + aseg * 16;

  const int brow = lane / CH;
  const int bcol = 8 * ((lane % CH) ^ (brow & (CH - 1)));
  const unsigned short* bSrc = Bt + (size_t)brow * ldb + k0 + bcol;

  for (int ks = 0; ks < kLen; ks += BK) {
    __syncthreads();
    // ---- issue B loads (async, no VGPR round-trip) ----
    #pragma unroll
    for (int i = 0; i < SLABW; ++i) {
      const int s = wid * SLABW + i;
      __builtin_amdgcn_global_load_lds(
          (const __attribute__((address_space(1))) uint32_t*)(bSrc + (size_t)s * RPS * ldb + ks),
          (__attribute__((address_space(3))) uint32_t*)(&Bs[s * 512]),
          16, 0, 0);
    }
    // ---- stage A: f32 -> bf16, swizzled 16B chunks ----
    {
      const float* ap = aBase + ks;
      f32x4 v0 = *(const f32x4*)(ap + 0);
      f32x4 v1 = *(const f32x4*)(ap + 4);
      f32x4 v2 = *(const f32x4*)(ap + 8);
      f32x4 v3 = *(const f32x4*)(ap + 12);
      if (RELU_A) {
        #pragma unroll
        for (int j = 0; j < 4; ++j) {
          v0[j] = fmaxf(v0[j], 0.f); v1[j] = fmaxf(v1[j], 0.f);
          v2[j] = fmaxf(v2[j], 0.f); v3[j] = fmaxf(v3[j], 0.f);
        }
      }
      short8 s0, s1;
      s0[0]=f2bf(v0[0]); s0[1]=f2bf(v0[1]); s0[2]=f2bf(v0[2]); s0[3]=f2bf(v0[3]);
      s0[4]=f2bf(v1[0]); s0[5]=f2bf(v1[1]); s0[6]=f2bf(v1[2]); s0[7]=f2bf(v1[3]);
      s1[0]=f2bf(v2[0]); s1[1]=f2bf(v2[1]); s1[2]=f2bf(v2[2]); s1[3]=f2bf(v2[3]);
      s1[4]=f2bf(v3[0]); s1[5]=f2bf(v3[1]); s1[6]=f2bf(v3[2]); s1[7]=f2bf(v3[3]);
      const int g0 = (aseg * 2)     ^ (am & 7);
      const int g1 = (aseg * 2 + 1) ^ (am & 7);
      *(short8*)&As[am * BK + g0 * 8] = s0;
      *(short8*)&As[am * BK + g1 * 8] = s1;
    }
    __syncthreads();
    // ---- compute ----
    #pragma unroll
    for (int kk = 0; kk < BK / 32; ++kk) {
      const int gk = kk * 4 + lg;
      short8 af[MF], bfr[NF];
      #pragma unroll
      for (int fm = 0; fm < MF; ++fm) {
        const int m = wrow * WTM + fm * 16 + l16;
        af[fm] = *(const short8*)&As[m * BK + ((gk ^ (m & 7)) * 8)];
      }
      #pragma unroll
      for (int fn = 0; fn < NF; ++fn) {
        const int n = wcol * WTN + fn * 16 + l16;
        bfr[fn] = *(const short8*)&Bs[n * BK + ((gk ^ (n & 7)) * 8)];
      }
      #pragma unroll
      for (int fm = 0; fm < MF; ++fm)
        #pragma unroll
        for (int fn = 0; fn < NF; ++fn)
          acc[fm][fn] = __builtin_amdgcn_mfma_f32_16x16x32_bf16(
              af[fm], bfr[fn], acc[fm][fn], 0, 0, 0);
    }
  }
  #pragma unroll
  for (int fm = 0; fm < MF; ++fm)
    #pragma unroll
    for (int fn = 0; fn < NF; ++fn)
      #pragma unroll
      for (int j = 0; j < 4; ++j) {
        const int r = mt * BM + wrow * WTM + fm * 16 + lg * 4 + j;
        const int c = wcol * WTN + fn * 16 + l16;
        atomicAdd(&C[(size_t)r * ldc + c], scale * acc[fm][fn][j]);
      }
}

// ---------------------------------------------------------------------------
// gemm_stream — gemm4 only. BM=64, BN=64, BK=64, 4 waves, WN=1 (wave owns
// 16 rows x 64 cols). A loaded DIRECT global->reg in MFMA fragment layout
// (layout HW-verified in R5). B double-buffered in LDS via global_load_lds
// with COUNTED vmcnt across a raw s_barrier: B's 2 loads are issued first
// (sched_barrier pins order), A's 4 loads after; s_waitcnt vmcnt(4) retires
// exactly B before the barrier, A stays in flight into the next iteration.
// ---------------------------------------------------------------------------
template<int MINW>
__global__ __launch_bounds__(256, MINW)
void gemm_stream(const float* __restrict__ A, int lda,
                 const unsigned short* __restrict__ Bt, int ldb,
                 float* __restrict__ C, int ldc,
                 int K, int kChunks, float scale)
{
  constexpr int BN = 64, BK = 64;
  constexpr int NF = BN / 16;        // 4
  constexpr int CH = BK / 8;         // 8
  constexpr int RPS = 512 / BK;      // 8 rows per 1KB slab
  constexpr int SLABW = (BN / RPS) / 4;  // 2 slabs per wave

  const int mt   = blockIdx.x / kChunks;
  const int kc   = blockIdx.x % kChunks;
  const int kLen = K / kChunks;
  const int k0   = kc * kLen;
  const int nt   = kLen / BK;
  const int tid  = threadIdx.x;
  const int lane = tid & 63;
  const int wid  = tid >> 6;
  const int l16  = lane & 15;
  const int lg   = lane >> 4;

  __shared__ unsigned short Bs[2][BN * BK];   // 2 x 8KB

  // A: fragment-layout direct load. lane (l16,lg) -> row l16, k = lg*8..+7.
  const int r = mt * 64 + wid * 16 + l16;
  const float* aPtr = A + (size_t)r * lda + k0 + lg * 8;

  // B staging: linear LDS dest + pre-swizzled global source.
  const int brow = lane / CH;
  const int bcol = 8 * ((lane % CH) ^ (brow & (CH - 1)));
  const unsigned short* bSrc = Bt + (size_t)brow * ldb + k0 + bcol;

  f32x4 acc[NF] = {};
  f32x4 av[4];          // A regs for one K-step (16 f32)
  short8 af0, af1;      // converted A fragments

  auto issueB = [&](int buf, int t) {
    #pragma unroll
    for (int i = 0; i < SLABW; ++i) {
      const int s = wid * SLABW + i;
      __builtin_amdgcn_global_load_lds(
          (const __attribute__((address_space(1))) uint32_t*)(bSrc + (size_t)s * RPS * ldb + t * BK),
          (__attribute__((address_space(3))) uint32_t*)(&Bs[buf][s * 512]),
          16, 0, 0);
    }
  };
  auto loadA = [&](int t) {
    #pragma unroll
    for (int kk = 0; kk < 2; ++kk) {
      av[2 * kk]     = *(const f32x4*)(aPtr + t * BK + kk * 32);
      av[2 * kk + 1] = *(const f32x4*)(aPtr + t * BK + kk * 32 + 4);
    }
  };
  auto cvtA = [&]() {
    af0[0]=f2bf(av[0][0]); af0[1]=f2bf(av[0][1]); af0[2]=f2bf(av[0][2]); af0[3]=f2bf(av[0][3]);
    af0[4]=f2bf(av[1][0]); af0[5]=f2bf(av[1][1]); af0[6]=f2bf(av[1][2]); af0[7]=f2bf(av[1][3]);
    af1[0]=f2bf(av[2][0]); af1[1]=f2bf(av[2][1]); af1[2]=f2bf(av[2][2]); af1[3]=f2bf(av[2][3]);
    af1[4]=f2bf(av[3][0]); af1[5]=f2bf(av[3][1]); af1[6]=f2bf(av[3][2]); af1[7]=f2bf(av[3][3]);
  };
  auto mfmaStep = [&](int buf) {
    #pragma unroll
    for (int kk = 0; kk < 2; ++kk) {
      const short8 afk = kk ? af1 : af0;
      #pragma unroll
      for (int fn = 0; fn < NF; ++fn) {
        const int n = fn * 16 + l16;
        short8 b = *(const short8*)&Bs[buf][n * BK + (((kk * 4 + lg) ^ (n & (CH - 1))) * 8)];
        acc[fn] = __builtin_amdgcn_mfma_f32_16x16x32_bf16(afk, b, acc[fn], 0, 0, 0);
      }
    }
  };

  // ---- prologue: B(0) oldest, then A(0); retire exactly B, keep A flying ----
  issueB(0, 0);
  __builtin_amdgcn_sched_barrier(0);
  loadA(0);
  asm volatile("s_waitcnt vmcnt(4)" ::: "memory");   // B(0)'s 2 loads retired
  __builtin_amdgcn_s_barrier();
  __builtin_amdgcn_sched_barrier(0);

  int buf = 0;
  for (int t = 0; t < nt; ++t) {
    cvtA();                                   // waits A(t) (compiler vmcnt), converts
    if (t + 1 < nt) {
      issueB(buf ^ 1, t + 1);                 // B(t+1): oldest outstanding
      __builtin_amdgcn_sched_barrier(0);      // pin: B issued before A
      loadA(t + 1);                           // A(t+1): 4 loads, stay in flight
    }
    mfmaStep(buf);                            // ds_read + MFMA on current buffer
    if (t + 1 < nt) {
      asm volatile("s_waitcnt vmcnt(4)" ::: "memory");  // retire B(t+1) only
      __builtin_amdgcn_s_barrier();           // raw: no full drain
      __builtin_amdgcn_sched_barrier(0);
    }
    buf ^= 1;
  }

  // epilogue: scaled f32 atomic add. C/D frag: col=l16, row=lg*4+j.
  #pragma unroll
  for (int fn = 0; fn < NF; ++fn)
    #pragma unroll
    for (int j = 0; j < 4; ++j) {
      const int rr = mt * 64 + wid * 16 + lg * 4 + j;
      const int cc = fn * 16 + l16;
      atomicAdd(&C[(size_t)rr * ldc + cc], scale * acc[fn][j]);
    }
}

// transpose-convert weights: W1t[j][i] = bf16(W1[i][j]), W2t likewise
__global__ void conv_w_t(const float* __restrict__ W1, const float* __restrict__ W2,
                         unsigned short* __restrict__ W1t, unsigned short* __restrict__ W2t) {
  const int idx = blockIdx.x * 256 + threadIdx.x;
  if (idx < D_IN * D_HID) {
    const int j = idx / D_IN, i = idx % D_IN;
    W1t[idx] = f2bf(W1[(size_t)i * D_HID + j]);
  }
  if (idx < D_HID * D_OUT) {
    const int j = idx / D_HID, i = idx % D_HID;
    W2t[idx] = f2bf(W2[(size_t)i * D_OUT + j]);
  }
}

// BextT[c][rows[r]] = bf16(relu(G[r][c] + bias[c]))   (BextT pre-zeroed)
__global__ void ep_scatter_t(const float* __restrict__ G, const float* __restrict__ bias,
                             const int* __restrict__ rows, unsigned short* __restrict__ BextT,
                             int ncol, int total) {
  const int idx = blockIdx.x * 256 + threadIdx.x;
  if (idx >= total) return;
  const int c = idx / S_SAMP;
  const int r = idx & (S_SAMP - 1);
  float v = G[(size_t)r * ncol + c] + bias[c];
  v = v > 0.f ? v : 0.f;
  BextT[(size_t)c * N_NODES + rows[r]] = f2bf(v);
}

extern "C" void kernel_launch(void* const* d_in, const int* in_sizes, int n_in,
                              void* d_out, int out_size, void* d_ws, size_t ws_size,
                              hipStream_t stream) {
  const float* X     = (const float*)d_in[0];
  const float* A_hat = (const float*)d_in[1];
  const float* W1    = (const float*)d_in[2];
  const float* b1    = (const float*)d_in[3];
  const float* W2    = (const float*)d_in[4];
  const float* b2    = (const float*)d_in[5];
  const int*   l0    = (const int*)d_in[6];
  const int*   l1    = (const int*)d_in[7];
  float* out = (float*)d_out;

  if (ws_size < (size_t)(20u << 20)) return;
  char* ws = (char*)d_ws;
  unsigned short* HextT = (unsigned short*)(ws);                      // [256][16384] 8MB
  unsigned short* PextT = (unsigned short*)(ws + (8  << 20));         // [64][16384]  2MB
  float* G1 = (float*)(ws + (10 << 20));                              // [S][256] 4MB
  float* G2 = (float*)(ws + (14 << 20));                              // [S][256] 4MB
  float* G3 = (float*)(ws + (18 << 20));                              // [S][64]  1MB
  unsigned short* W1t = (unsigned short*)(ws + (19 << 20));           // [256][512]
  unsigned short* W2t = (unsigned short*)(ws + (19 << 20) + (256 << 10)); // [64][256]

  hipMemsetAsync(ws,  0, (size_t)(19u << 20), stream);
  hipMemsetAsync(out, 0, (size_t)N_NODES * D_OUT * 4, stream);

  conv_w_t<<<512, 256, 0, stream>>>(W1, W2, W1t, W2t);

  // L0 feature: G1 = X[l0] @ W1          M=4096 K=512 N=256 (512 blocks)
  gemm_tn<64, 256, 64, false><<<(S_SAMP / 64) * 8, 256, 0, stream>>>(
      X, D_IN, l0, W1t, D_IN, G1, D_HID, D_IN, 8, 1.0f);
  ep_scatter_t<<<(S_SAMP * D_HID + 255) / 256, 256, 0, stream>>>(
      G1, b1, l0, HextT, D_HID, S_SAMP * D_HID);

  // L0 agg: G2 = 4 * A_hat[l1, :] @ Hext  M=4096 K=16384 N=256 (1024 blocks, 4/CU)
  gemm_tn<64, 256, 64, false><<<(S_SAMP / 64) * 16, 256, 0, stream>>>(
      A_hat, N_NODES, l1, HextT, N_NODES, G2, D_HID, N_NODES, 16, 4.0f);

  // L1 feature: G3 = relu(G2) @ W2        M=4096 K=256 N=64
  gemm_tn<64, 64, 64, true><<<(S_SAMP / 64) * 4, 256, 0, stream>>>(
      G2, D_HID, nullptr, W2t, D_HID, G3, D_OUT, D_HID, 4, 1.0f);
  ep_scatter_t<<<(S_SAMP * D_OUT + 255) / 256, 256, 0, stream>>>(
      G3, b2, l1, PextT, D_OUT, S_SAMP * D_OUT);

  // L1 agg: out = 4 * A_hat @ Pext        M=16384 K=16384 N=64 (2048 blocks, counted-vmcnt)
  gemm_stream<6><<<(N_NODES / 64) * 8, 256, 0, stream>>>(
      A_hat, N_NODES, PextT, N_NODES, out, D_OUT, N_NODES, 8, 4.0f);
}

// Round 7
// 383.526 us; speedup vs baseline: 1.1236x; 1.0734x over previous
//
#include <hip/hip_runtime.h>
#include <hip/hip_bf16.h>
#include <stdint.h>

typedef __attribute__((ext_vector_type(8))) short short8;
typedef __attribute__((ext_vector_type(4))) float f32x4;

#define N_NODES 16384
#define D_IN    512
#define D_HID   256
#define D_OUT   64
#define S_SAMP  4096

__device__ __forceinline__ unsigned short f2bf(float f) {
  __hip_bfloat16 h = __float2bfloat16(f);
  union { __hip_bfloat16 h; unsigned short u; } cv; cv.h = h; return cv.u;
}

// ---------------------------------------------------------------------------
// gemm_tn — R2 baseline form: single-buffered As/Bs, BK=64, two barriers per
// K-step. kc-MAJOR block ordering: co-dispatched blocks share the same B-slab
// (L2-resident) and stream A as a column-panel.
// ---------------------------------------------------------------------------
template<int BM, int BN, int BK, bool RELU_A>
__global__ __launch_bounds__(256)
void gemm_tn(const float* __restrict__ A, int lda,
             const int* __restrict__ arow,
             const unsigned short* __restrict__ Bt, int ldb,
             float* __restrict__ C, int ldc,
             int K, int kChunks, float scale)
{
  static_assert(BM == 64 && BK == 64 && (BN == 64 || BN == 256), "tile");
  constexpr int CH    = BK / 8;
  constexpr int RPS   = 512 / BK;
  constexpr int SLABS = BN / RPS;
  constexpr int SLABW = SLABS / 4;

  // kc-major: blocks [kc*nMt, (kc+1)*nMt) all share K-chunk kc -> same B-slab.
  const int nMt = gridDim.x / kChunks;
  const int mt  = blockIdx.x % nMt;
  const int kc  = blockIdx.x / nMt;
  const int kLen = K / kChunks;
  const int k0   = kc * kLen;
  const int tid  = threadIdx.x;
  const int lane = tid & 63;
  const int wid  = tid >> 6;
  const int l16  = lane & 15;
  const int lg   = lane >> 4;

  __shared__ unsigned short As[BM * BK];
  __shared__ unsigned short Bs[BN * BK];

  constexpr int WN  = (BN == 256) ? 4 : 2;
  constexpr int WM  = 4 / WN;
  constexpr int WTM = BM / WM;
  constexpr int WTN = BN / WN;
  constexpr int MF  = WTM / 16;
  constexpr int NF  = WTN / 16;
  const int wrow = wid / WN;
  const int wcol = wid % WN;

  f32x4 acc[MF][NF] = {};

  const int am   = tid >> 2;
  const int aseg = tid & 3;
  const int arowIdx = mt * BM + am;
  const size_t rowg = arow ? (size_t)arow[arowIdx] : (size_t)arowIdx;
  const float* aBase = A + rowg * (size_t)lda + k0 + aseg * 16;

  const int brow = lane / CH;
  const int bcol = 8 * ((lane % CH) ^ (brow & (CH - 1)));
  const unsigned short* bSrc = Bt + (size_t)brow * ldb + k0 + bcol;

  for (int ks = 0; ks < kLen; ks += BK) {
    __syncthreads();
    // ---- issue B loads (async, no VGPR round-trip) ----
    #pragma unroll
    for (int i = 0; i < SLABW; ++i) {
      const int s = wid * SLABW + i;
      __builtin_amdgcn_global_load_lds(
          (const __attribute__((address_space(1))) uint32_t*)(bSrc + (size_t)s * RPS * ldb + ks),
          (__attribute__((address_space(3))) uint32_t*)(&Bs[s * 512]),
          16, 0, 0);
    }
    // ---- stage A: f32 -> bf16, swizzled 16B chunks ----
    {
      const float* ap = aBase + ks;
      f32x4 v0 = *(const f32x4*)(ap + 0);
      f32x4 v1 = *(const f32x4*)(ap + 4);
      f32x4 v2 = *(const f32x4*)(ap + 8);
      f32x4 v3 = *(const f32x4*)(ap + 12);
      if (RELU_A) {
        #pragma unroll
        for (int j = 0; j < 4; ++j) {
          v0[j] = fmaxf(v0[j], 0.f); v1[j] = fmaxf(v1[j], 0.f);
          v2[j] = fmaxf(v2[j], 0.f); v3[j] = fmaxf(v3[j], 0.f);
        }
      }
      short8 s0, s1;
      s0[0]=f2bf(v0[0]); s0[1]=f2bf(v0[1]); s0[2]=f2bf(v0[2]); s0[3]=f2bf(v0[3]);
      s0[4]=f2bf(v1[0]); s0[5]=f2bf(v1[1]); s0[6]=f2bf(v1[2]); s0[7]=f2bf(v1[3]);
      s1[0]=f2bf(v2[0]); s1[1]=f2bf(v2[1]); s1[2]=f2bf(v2[2]); s1[3]=f2bf(v2[3]);
      s1[4]=f2bf(v3[0]); s1[5]=f2bf(v3[1]); s1[6]=f2bf(v3[2]); s1[7]=f2bf(v3[3]);
      const int g0 = (aseg * 2)     ^ (am & 7);
      const int g1 = (aseg * 2 + 1) ^ (am & 7);
      *(short8*)&As[am * BK + g0 * 8] = s0;
      *(short8*)&As[am * BK + g1 * 8] = s1;
    }
    __syncthreads();
    // ---- compute ----
    #pragma unroll
    for (int kk = 0; kk < BK / 32; ++kk) {
      const int gk = kk * 4 + lg;
      short8 af[MF], bfr[NF];
      #pragma unroll
      for (int fm = 0; fm < MF; ++fm) {
        const int m = wrow * WTM + fm * 16 + l16;
        af[fm] = *(const short8*)&As[m * BK + ((gk ^ (m & 7)) * 8)];
      }
      #pragma unroll
      for (int fn = 0; fn < NF; ++fn) {
        const int n = wcol * WTN + fn * 16 + l16;
        bfr[fn] = *(const short8*)&Bs[n * BK + ((gk ^ (n & 7)) * 8)];
      }
      #pragma unroll
      for (int fm = 0; fm < MF; ++fm)
        #pragma unroll
        for (int fn = 0; fn < NF; ++fn)
          acc[fm][fn] = __builtin_amdgcn_mfma_f32_16x16x32_bf16(
              af[fm], bfr[fn], acc[fm][fn], 0, 0, 0);
    }
  }
  #pragma unroll
  for (int fm = 0; fm < MF; ++fm)
    #pragma unroll
    for (int fn = 0; fn < NF; ++fn)
      #pragma unroll
      for (int j = 0; j < 4; ++j) {
        const int r = mt * BM + wrow * WTM + fm * 16 + lg * 4 + j;
        const int c = wcol * WTN + fn * 16 + l16;
        atomicAdd(&C[(size_t)r * ldc + c], scale * acc[fm][fn][j]);
      }
}

// transpose-convert weights: W1t[j][i] = bf16(W1[i][j]), W2t likewise
__global__ void conv_w_t(const float* __restrict__ W1, const float* __restrict__ W2,
                         unsigned short* __restrict__ W1t, unsigned short* __restrict__ W2t) {
  const int idx = blockIdx.x * 256 + threadIdx.x;
  if (idx < D_IN * D_HID) {
    const int j = idx / D_IN, i = idx % D_IN;
    W1t[idx] = f2bf(W1[(size_t)i * D_HID + j]);
  }
  if (idx < D_HID * D_OUT) {
    const int j = idx / D_HID, i = idx % D_HID;
    W2t[idx] = f2bf(W2[(size_t)i * D_OUT + j]);
  }
}

// BextT[c][rows[r]] = bf16(relu(G[r][c] + bias[c]))   (BextT pre-zeroed)
__global__ void ep_scatter_t(const float* __restrict__ G, const float* __restrict__ bias,
                             const int* __restrict__ rows, unsigned short* __restrict__ BextT,
                             int ncol, int total) {
  const int idx = blockIdx.x * 256 + threadIdx.x;
  if (idx >= total) return;
  const int c = idx / S_SAMP;
  const int r = idx & (S_SAMP - 1);
  float v = G[(size_t)r * ncol + c] + bias[c];
  v = v > 0.f ? v : 0.f;
  BextT[(size_t)c * N_NODES + rows[r]] = f2bf(v);
}

extern "C" void kernel_launch(void* const* d_in, const int* in_sizes, int n_in,
                              void* d_out, int out_size, void* d_ws, size_t ws_size,
                              hipStream_t stream) {
  const float* X     = (const float*)d_in[0];
  const float* A_hat = (const float*)d_in[1];
  const float* W1    = (const float*)d_in[2];
  const float* b1    = (const float*)d_in[3];
  const float* W2    = (const float*)d_in[4];
  const float* b2    = (const float*)d_in[5];
  const int*   l0    = (const int*)d_in[6];
  const int*   l1    = (const int*)d_in[7];
  float* out = (float*)d_out;

  if (ws_size < (size_t)(20u << 20)) return;
  char* ws = (char*)d_ws;
  unsigned short* HextT = (unsigned short*)(ws);                      // [256][16384] 8MB
  unsigned short* PextT = (unsigned short*)(ws + (8  << 20));         // [64][16384]  2MB
  float* G1 = (float*)(ws + (10 << 20));                              // [S][256] 4MB
  float* G2 = (float*)(ws + (14 << 20));                              // [S][256] 4MB
  float* G3 = (float*)(ws + (18 << 20));                              // [S][64]  1MB
  unsigned short* W1t = (unsigned short*)(ws + (19 << 20));           // [256][512]
  unsigned short* W2t = (unsigned short*)(ws + (19 << 20) + (256 << 10)); // [64][256]

  hipMemsetAsync(ws,  0, (size_t)(19u << 20), stream);
  hipMemsetAsync(out, 0, (size_t)N_NODES * D_OUT * 4, stream);

  conv_w_t<<<512, 256, 0, stream>>>(W1, W2, W1t, W2t);

  // L0 feature: G1 = X[l0] @ W1          M=4096 K=512 N=256 (512 blocks, 2/CU)
  gemm_tn<64, 256, 64, false><<<(S_SAMP / 64) * 8, 256, 0, stream>>>(
      X, D_IN, l0, W1t, D_IN, G1, D_HID, D_IN, 8, 1.0f);
  ep_scatter_t<<<(S_SAMP * D_HID + 255) / 256, 256, 0, stream>>>(
      G1, b1, l0, HextT, D_HID, S_SAMP * D_HID);

  // L0 agg: G2 = 4 * A_hat[l1, :] @ Hext  M=4096 K=16384 N=256
  // (1024 blocks = 4/CU at 40KB LDS; kc-major -> 1MB B-slab shared per phase)
  gemm_tn<64, 256, 64, false><<<(S_SAMP / 64) * 16, 256, 0, stream>>>(
      A_hat, N_NODES, l1, HextT, N_NODES, G2, D_HID, N_NODES, 16, 4.0f);

  // L1 feature: G3 = relu(G2) @ W2        M=4096 K=256 N=64
  gemm_tn<64, 64, 64, true><<<(S_SAMP / 64) * 4, 256, 0, stream>>>(
      G2, D_HID, nullptr, W2t, D_HID, G3, D_OUT, D_HID, 4, 1.0f);
  ep_scatter_t<<<(S_SAMP * D_OUT + 255) / 256, 256, 0, stream>>>(
      G3, b2, l1, PextT, D_OUT, S_SAMP * D_OUT);

  // L1 agg: out = 4 * A_hat @ Pext        M=16384 K=16384 N=64
  // (2048 blocks = 8/CU; kc-major -> 256KB B-slab shared, A_hat column-panel stream)
  gemm_tn<64, 64, 64, false><<<(N_NODES / 64) * 8, 256, 0, stream>>>(
      A_hat, N_NODES, nullptr, PextT, N_NODES, out, D_OUT, N_NODES, 8, 4.0f);
}